// Round 6
// baseline (48.593 us; speedup 1.0000x reference)
//
#include <hip/hip_runtime.h>

// dist[b,k,n] = sqrt(max(||m||^2 + ||c||^2 - 2 c.m, 0))
// M: (B=4, D=8, N=65536) f32, centroids: (K=256, D=8) f32, out: (B,K,N) f32.
// Store-BW bound: 268 MB output. R4 post-mortem: 302 MB total at 6.27 TB/s =
// 91% of the machine's demonstrated fill rate; remaining slack = M re-reads.
// KCHUNK=128 halves them (17 MB total). Grid (64,4,2)=512 blocks = 8 waves/CU,
// still >>3.4 waves/CU at which fillBuffer saturates write BW. (y,z)-keyed
// phase stagger keeps the 64 x-blocks of each group in lockstep writing
// contiguous 256 KB planes (8 fill-like streams). Plain float4 stores
// (nontemporal regressed). LDS stages c2=-2c, ||c||^2; inner loop:
// acc = msq+csq; 8 fma; v_sqrt(max).

constexpr int B = 4;
constexpr int D = 8;
constexpr int N = 65536;
constexpr int K = 256;
constexpr int VEC = 4;
constexpr int TPB = 256;
constexpr int KCHUNK = 128;
constexpr int NBLK_X = N / (TPB * VEC);  // 64

__global__ __launch_bounds__(TPB) void ComputeDistances_82317343195698_kernel(
    const float* __restrict__ M, const float* __restrict__ C,
    float* __restrict__ out) {
  __shared__ float sc2[KCHUNK][D];  // -2 * c[k][d]
  __shared__ float scsq[KCHUNK];    // ||c[k]||^2

  const int tid = threadIdx.x;
  const int b = blockIdx.y;
  const int k0 = blockIdx.z * KCHUNK;

  if (tid < KCHUNK) {
    const float4* c4 = reinterpret_cast<const float4*>(C + (size_t)(k0 + tid) * D);
    float4 a = c4[0];
    float4 e = c4[1];
    scsq[tid] = a.x * a.x + a.y * a.y + a.z * a.z + a.w * a.w +
                e.x * e.x + e.y * e.y + e.z * e.z + e.w * e.w;
    sc2[tid][0] = -2.f * a.x; sc2[tid][1] = -2.f * a.y;
    sc2[tid][2] = -2.f * a.z; sc2[tid][3] = -2.f * a.w;
    sc2[tid][4] = -2.f * e.x; sc2[tid][5] = -2.f * e.y;
    sc2[tid][6] = -2.f * e.z; sc2[tid][7] = -2.f * e.w;
  }
  __syncthreads();

  const int n0 = (blockIdx.x * TPB + tid) * VEC;

  // Load this thread's 4 columns of M and their squared norms.
  float m[D][VEC];
  float msq[VEC] = {0.f, 0.f, 0.f, 0.f};
#pragma unroll
  for (int d = 0; d < D; ++d) {
    float4 v = *reinterpret_cast<const float4*>(M + ((size_t)(b * D + d) * N + n0));
    m[d][0] = v.x; m[d][1] = v.y; m[d][2] = v.z; m[d][3] = v.w;
#pragma unroll
    for (int j = 0; j < VEC; ++j) msq[j] = fmaf(m[d][j], m[d][j], msq[j]);
  }

  float* outp = out + ((size_t)(b * K + k0) * N + n0);

  // Stagger keyed on (y,z) ONLY: x-adjacent blocks stay in lockstep, writing
  // contiguous planes; the 8 (y,z) groups start at decorrelated k-offsets.
  const int phase = ((blockIdx.y * 2 + blockIdx.z) * 16 + blockIdx.z) & (KCHUNK - 1);

#pragma unroll 8
  for (int i = 0; i < KCHUNK; ++i) {
    const int kk = (i + phase) & (KCHUNK - 1);
    float c[D];
#pragma unroll
    for (int d = 0; d < D; ++d) c[d] = sc2[kk][d];  // wave-uniform LDS broadcast
    const float cs = scsq[kk];

    float4 r;
    float* rp = &r.x;
#pragma unroll
    for (int j = 0; j < VEC; ++j) {
      float acc = msq[j] + cs;
#pragma unroll
      for (int d = 0; d < D; ++d) acc = fmaf(c[d], m[d][j], acc);
      rp[j] = __builtin_amdgcn_sqrtf(fmaxf(acc, 0.f));
    }
    *reinterpret_cast<float4*>(outp + (size_t)kk * N) = r;
  }
}

extern "C" void kernel_launch(void* const* d_in, const int* in_sizes, int n_in,
                              void* d_out, int out_size, void* d_ws, size_t ws_size,
                              hipStream_t stream) {
  const float* M = (const float*)d_in[0];
  const float* C = (const float*)d_in[1];
  float* out = (float*)d_out;

  dim3 grid(NBLK_X, B, K / KCHUNK);  // (64, 4, 2) = 512 blocks
  dim3 block(TPB);
  ComputeDistances_82317343195698_kernel<<<grid, block, 0, stream>>>(M, C, out);
}